// Round 14
// baseline (127.587 us; speedup 1.0000x reference)
//
#include <hip/hip_runtime.h>
#include <math.h>

#define BSZ    8192
#define DDIM   256
#define SCALE  33.33333333333333f   // 1/0.03
#define C_OFF  34.0f                // fixed LSE offset: |sim*SCALE| <= 33.34
#define SC_L2E 48.08983470f         // SCALE * log2(e)
#define C2     49.05163139f         // C_OFF * log2(e)

typedef float floatx4 __attribute__((ext_vector_type(4)));
typedef long long fp8x8;            // 8 x fp8 e4m3 = one MFMA operand (2 VGPRs)

// pack 8 fp32 -> 8 fp8 e4m3 (HW cvt; format matches the fp8 MFMA operand)
__device__ __forceinline__ fp8x8 cvt8_f8(const float* __restrict__ g)
{
    const float4 lo = *(const float4*)g;
    const float4 hi = *(const float4*)(g + 4);
    int a = __builtin_amdgcn_cvt_pk_fp8_f32(lo.x, lo.y, 0, false);
    a     = __builtin_amdgcn_cvt_pk_fp8_f32(lo.z, lo.w, a, true);
    int b = __builtin_amdgcn_cvt_pk_fp8_f32(hi.x, hi.y, 0, false);
    b     = __builtin_amdgcn_cvt_pk_fp8_f32(hi.z, hi.w, b, true);
    int2 r; r.x = a; r.y = b;
    return *(fp8x8*)&r;
}

// ---------------------------------------------------------------- prep (zt only)
// zt -> zt_perm (fp8), chunk-ordered: 4KB g-chunk = (colblock cb, kc);
// 8-B slot P (0..511) holds col cb*128+(P>>2), k = kc*32 + ((P&3)^(((P>>2)>>2)&3))*8
// (R13-verified conflict-free image). blocks<16 zero s_row/s_col + scalars.
__global__ __launch_bounds__(256) void prep_kernel(
    const float* __restrict__ zt, unsigned char* __restrict__ zt_perm,
    float* __restrict__ zbase)
{
    const int bid = blockIdx.x, tid = threadIdx.x;
    const int S     = bid * 256 + tid;            // global 8-B slot id
    const int chunk = S >> 9, P = S & 511;
    const int col   = P >> 2, sp = P & 3;
    const int sl    = sp ^ ((col >> 2) & 3);
    const int cb    = chunk >> 3, kc = chunk & 7;
    const float* src = zt + (size_t)(cb * 128 + col) * DDIM + kc * 32 + sl * 8;
    *(fp8x8*)(zt_perm + (size_t)S * 8) = cvt8_f8(src);

    if (bid < 16) {
        const int z = bid * 1024 + tid * 4;
        *(float4*)&zbase[z] = (float4){0.f, 0.f, 0.f, 0.f};
        if (bid == 0 && tid == 0) {
            zbase[16384] = 0.f;          // total
            ((int*)zbase)[16385] = 0;    // flag
            ((int*)zbase)[16386] = 0;    // cnt
        }
    }
}

// ---------------------------------------------------------------- sim (R13 core, 2 deltas)
// Delta 1 vs R13: 8KB chunks (2 issues/wave), 2x8KB buffers -> 16 barriers
//   (was 32). ONLY the chunk size changes — the R8 regression was confounded.
// Delta 2 vs R13: A converted fp32->fp8 in-register in the prologue (R4/R7-
//   proven); prep is zt-only.
// Everything else byte-identical to R13 (best-known-good, 55.5 us).
__global__ __launch_bounds__(256, 2) void sim_fused(
    const float* __restrict__ za, const unsigned char* __restrict__ zt_perm,
    const int* __restrict__ pid,
    float* __restrict__ s_row, float* __restrict__ s_col,
    float* __restrict__ posv)
{
    __shared__ __align__(16) unsigned char Bs[2][8192];   // 2 x 8 KB
    __shared__ int   pidc[512];
    __shared__ float colsum[512];

    const int bid   = blockIdx.x;
    const int strip = bid & 15, band = bid >> 4;
    const int row0  = band * 128, scol0 = strip * 512;
    const int tid   = threadIdx.x, lane = tid & 63, wid = tid >> 6;
    const int q     = lane >> 4, lc = lane & 15;
    const int rbase = row0 + wid * 32;
    const int qs8   = (q ^ ((lc >> 2) & 3)) * 8;   // swizzled 8-B k-slot offset

    pidc[tid]         = pid[scol0 + tid];
    pidc[tid + 256]   = pid[scol0 + tid + 256];
    colsum[tid]       = 0.f;
    colsum[tid + 256] = 0.f;

    // A resident: af[m][kc] = A[rbase+m*16+lc][kc*32 + q*8 ..+8], fp32->fp8 cvt
    fp8x8 af[2][8];
    #pragma unroll
    for (int m = 0; m < 2; m++) {
        const float* ga = za + (size_t)(rbase + m * 16 + lc) * DDIM + q * 8;
        #pragma unroll
        for (int kc = 0; kc < 8; kc++)
            af[m][kc] = cvt8_f8(ga + kc * 32);
    }

    int prw[2][4];
    #pragma unroll
    for (int m = 0; m < 2; m++)
        #pragma unroll
        for (int r = 0; r < 4; r++)
            prw[m][r] = pid[rbase + m * 16 + q * 4 + r];

    // staging: 8KB chunk C (0..15) of this strip = zt_perm bytes
    // [(strip*32)*4096 + C*8192, +8192); 4 waves x 2 width-16 issues cover it.
    const unsigned char* zp = zt_perm + (size_t)(strip * 32) * 4096
                            + wid * 1024 + lane * 16;

#define STAGE(C, b)                                                              \
    do {                                                                         \
        const unsigned char* _s = zp + (size_t)(C) * 8192;                       \
        unsigned char* _d = &Bs[b][0] + wid * 1024;                              \
        __builtin_amdgcn_global_load_lds(                                        \
            (const __attribute__((address_space(1))) void*)_s,                   \
            (__attribute__((address_space(3))) void*)_d, 16, 0, 0);              \
        __builtin_amdgcn_global_load_lds(                                        \
            (const __attribute__((address_space(1))) void*)(_s + 4096),          \
            (__attribute__((address_space(3))) void*)(_d + 4096), 16, 0, 0);     \
    } while (0)

    STAGE(0, 0);   // prologue

    float rowp[8] = {0.f, 0.f, 0.f, 0.f, 0.f, 0.f, 0.f, 0.f};
    const int diag_t = (row0 - scol0) >> 7;   // tile holding the diagonal (if in [0,4))

    for (int t = 0; t < 4; t++) {
        floatx4 acc[2][8];
        #pragma unroll
        for (int m = 0; m < 2; m++)
            #pragma unroll
            for (int n = 0; n < 8; n++)
                acc[m][n] = (floatx4){0.f, 0.f, 0.f, 0.f};

        #pragma unroll
        for (int c2 = 0; c2 < 4; c2++) {
            __syncthreads();                 // chunk C landed (vmcnt drain at barrier)
            const int C = t * 4 + c2;
            if (C + 1 < 16) STAGE(C + 1, (C + 1) & 1);   // fire-and-forget prefetch

            const unsigned char* B = &Bs[C & 1][0];
            #pragma unroll
            for (int j = 0; j < 2; j++) {    // two 32-k sub-chunks of the 8KB
                const int kc = c2 * 2 + j;
                fp8x8 bfr[8];
                #pragma unroll
                for (int n = 0; n < 8; n++)
                    bfr[n] = *(const fp8x8*)(B + j * 4096 + (n * 16 + lc) * 32 + qs8);

                #pragma unroll
                for (int m = 0; m < 2; m++)
                    #pragma unroll
                    for (int n = 0; n < 8; n++)
                        acc[m][n] = __builtin_amdgcn_mfma_f32_16x16x32_fp8_fp8(
                            af[m][kc], bfr[n], acc[m][n], 0, 0, 0);
            }
        }

        // ---------- epilogue for tile t (next chunk's prefetch in flight)
        int pc[8];
        #pragma unroll
        for (int n = 0; n < 8; n++) pc[n] = pidc[t * 128 + n * 16 + lc];

        float colp[8] = {0.f, 0.f, 0.f, 0.f, 0.f, 0.f, 0.f, 0.f};
        #pragma unroll
        for (int m = 0; m < 2; m++) {
            #pragma unroll
            for (int r = 0; r < 4; r++) {
                const int pr = prw[m][r];
                float rsum = 0.f;
                #pragma unroll
                for (int n = 0; n < 8; n++) {
                    float e = __builtin_amdgcn_exp2f(fmaf(acc[m][n][r], SC_L2E, -C2));
                    e = (pr != pc[n]) ? e : 0.f;
                    rsum += e;
                    colp[n] += e;
                }
                rowp[m * 4 + r] += rsum;
            }
        }

        if (t == diag_t) {   // uniform branch: add back the (always same-pid) diagonal.
            // CONSTANT-INDEX select chains only — dynamic reg-array indexing
            // demotes acc[] to scratch (R5: 1.66 GB HBM writes, 3x regression).
            #pragma unroll
            for (int m = 0; m < 2; m++) {
                const int nstar = wid * 2 + m;          // runtime value, fine
                #pragma unroll
                for (int r = 0; r < 4; r++) {
                    float v = 0.f;
                    #pragma unroll
                    for (int n = 0; n < 8; n++)
                        v = (n == nstar) ? acc[m][n][r] : v;   // cndmask chain
                    float e = __builtin_amdgcn_exp2f(fmaf(v, SC_L2E, -C2));
                    const bool own = (lc == q * 4 + r);
                    e = own ? e : 0.f;
                    rowp[m * 4 + r] += e;
                    #pragma unroll
                    for (int n = 0; n < 8; n++)
                        colp[n] += (n == nstar) ? e : 0.f;     // cndmask chain
                    if (own) posv[rbase + m * 16 + q * 4 + r] = v * SCALE;
                }
            }
        }

        #pragma unroll
        for (int n = 0; n < 8; n++) {
            colp[n] += __shfl_xor(colp[n], 16, 64);
            colp[n] += __shfl_xor(colp[n], 32, 64);
        }
        if (q == 0) {
            #pragma unroll
            for (int n = 0; n < 8; n++)
                atomicAdd(&colsum[t * 128 + n * 16 + lc], colp[n]);
        }
    }

    // ---------- row sums: reduce over lc (cols), one atomic per row
    #pragma unroll
    for (int i = 0; i < 8; i++) {
        rowp[i] += __shfl_xor(rowp[i], 1, 64);
        rowp[i] += __shfl_xor(rowp[i], 2, 64);
        rowp[i] += __shfl_xor(rowp[i], 4, 64);
        rowp[i] += __shfl_xor(rowp[i], 8, 64);
    }
    float rw = rowp[0];
    #pragma unroll
    for (int idx = 1; idx < 8; idx++)
        rw = (lc == idx) ? rowp[idx] : rw;
    if (lc < 8)
        atomicAdd(&s_row[rbase + (lc >> 2) * 16 + q * 4 + (lc & 3)], rw);

    // ---------- col sums
    __syncthreads();
    atomicAdd(&s_col[scol0 + tid], colsum[tid]);
    atomicAdd(&s_col[scol0 + tid + 256], colsum[tid + 256]);
#undef STAGE
}

// ---------------------------------------------------------------- finalize (+ scalar write)
__global__ __launch_bounds__(256) void finalize_rows(
    const int* __restrict__ pid,
    const float* __restrict__ s_row, const float* __restrict__ s_col,
    const float* __restrict__ posv,
    float* __restrict__ total, int* __restrict__ flag, int* __restrict__ cnt,
    float* __restrict__ out)
{
    const int i = blockIdx.x * 256 + threadIdx.x;
    const float p = posv[i];
    const float c = (logf(s_row[i]) + C_OFF - p)
                  + (logf(s_col[i]) + C_OFF - p);

    float v = c;
    #pragma unroll
    for (int off = 32; off > 0; off >>= 1) v += __shfl_down(v, off, 64);
    if ((threadIdx.x & 63) == 0) atomicAdd(total, v);

    const unsigned long long m = __ballot(pid[i] != pid[0]);
    if (m != 0ull && (threadIdx.x & 63) == 0) atomicOr(flag, 1);

    __syncthreads();
    __threadfence();
    if (threadIdx.x == 0) {
        const int done = atomicAdd(cnt, 1);
        if (done == (int)gridDim.x - 1) {
            const float t = atomicAdd(total, 0.0f);
            const int   f = atomicOr(flag, 0);
            out[0] = f ? t / (2.0f * (float)BSZ) : 0.0f;
        }
    }
}

// ---------------------------------------------------------------- launcher
extern "C" void kernel_launch(void* const* d_in, const int* in_sizes, int n_in,
                              void* d_out, int out_size, void* d_ws, size_t ws_size,
                              hipStream_t stream)
{
    const float* za  = (const float*)d_in[0];
    const float* zt  = (const float*)d_in[1];
    const int*   pid = (const int*)d_in[2];
    float* out = (float*)d_out;

    // ws: zt_perm 2MB | s_row[8192] s_col[8192] total flag cnt posv[8192]
    unsigned char* zt_perm = (unsigned char*)d_ws;
    float*  s_row   = (float*)(zt_perm + (size_t)BSZ * DDIM);
    float*  s_col   = s_row + BSZ;
    float*  total   = s_col + BSZ;
    int*    flag    = (int*)(total + 1);
    int*    cnt     = flag + 1;
    float*  posv    = (float*)(cnt + 1);

    prep_kernel<<<dim3(1024), 256, 0, stream>>>(zt, zt_perm, s_row);

    sim_fused<<<dim3(1024), 256, 0, stream>>>(za, zt_perm, pid,
                                              s_row, s_col, posv);

    finalize_rows<<<dim3(BSZ / 256), 256, 0, stream>>>(
        pid, s_row, s_col, posv, total, flag, cnt, out);
}

// Round 15
// 120.233 us; speedup vs baseline: 1.0612x; 1.0612x over previous
//
#include <hip/hip_runtime.h>
#include <math.h>

#define BSZ    8192
#define DDIM   256
#define SCALE  33.33333333333333f   // 1/0.03
#define C_OFF  34.0f                // fixed LSE offset: |sim*SCALE| <= 33.34
#define SC_L2E 48.08983470f         // SCALE * log2(e)
#define C2     49.05163139f         // C_OFF * log2(e)

typedef float floatx4 __attribute__((ext_vector_type(4)));
typedef long long fp8x8;            // 8 x fp8 e4m3 = one MFMA operand (2 VGPRs)

// pack 8 fp32 -> 8 fp8 e4m3 (HW cvt; format matches the fp8 MFMA operand)
__device__ __forceinline__ fp8x8 cvt8_f8(const float* __restrict__ g)
{
    const float4 lo = *(const float4*)g;
    const float4 hi = *(const float4*)(g + 4);
    int a = __builtin_amdgcn_cvt_pk_fp8_f32(lo.x, lo.y, 0, false);
    a     = __builtin_amdgcn_cvt_pk_fp8_f32(lo.z, lo.w, a, true);
    int b = __builtin_amdgcn_cvt_pk_fp8_f32(hi.x, hi.y, 0, false);
    b     = __builtin_amdgcn_cvt_pk_fp8_f32(hi.z, hi.w, b, true);
    int2 r; r.x = a; r.y = b;
    return *(fp8x8*)&r;
}

// ---------------------------------------------------------------- prep (R13-identical)
// blocks [0,1024): za -> za_f8 (row-major fp8) + zero reduction ws (first 17 blocks)
// blocks [1024,2048): zt -> zt_perm (fp8), chunk-ordered: 4KB chunk = (cb, kc);
//   8-B slot P (0..511) holds col cb*128+(P>>2), k = kc*32 + ((P&3)^(((P>>2)>>2)&3))*8
//   (R13-verified conflict-free LDS image).
__global__ __launch_bounds__(256) void prep_kernel(
    const float* __restrict__ za, const float* __restrict__ zt,
    unsigned char* __restrict__ za_f8, unsigned char* __restrict__ zt_perm,
    float* __restrict__ zbase)
{
    const int bid = blockIdx.x, tid = threadIdx.x;
    if (bid < 1024) {
        const int i = (bid * 256 + tid) * 8;
        *(fp8x8*)(za_f8 + i) = cvt8_f8(za + i);
        if (bid < 16) {
            const int z = bid * 1024 + tid * 4;
            *(float4*)&zbase[z] = (float4){0.f, 0.f, 0.f, 0.f};
            if (bid == 0 && tid == 0) {
                zbase[16384] = 0.f;          // total
                ((int*)zbase)[16385] = 0;    // flag
                ((int*)zbase)[16386] = 0;    // cnt
            }
        }
    } else {
        const int S     = (bid - 1024) * 256 + tid;   // global 8-B slot id
        const int chunk = S >> 9, P = S & 511;
        const int col   = P >> 2, sp = P & 3;
        const int sl    = sp ^ ((col >> 2) & 3);
        const int cb    = chunk >> 3, kc = chunk & 7;
        const float* src = zt + (size_t)(cb * 128 + col) * DDIM + kc * 32 + sl * 8;
        *(fp8x8*)(zt_perm + (size_t)S * 8) = cvt8_f8(src);
    }
}

// ---------------------------------------------------------------- sim (R13 + ONE delta)
// SINGLE change vs R13 (best-known-good, sim 55.5us): 8KB staging chunks
// (2 global_load_lds issues/wave), 2x8KB buffers -> 16 K-loop barriers (was
// 32). A stays fp8 from za_f8 (R14's fp32-A refetch cost +25MB FETCH — reverted).
__global__ __launch_bounds__(256, 2) void sim_fused(
    const unsigned char* __restrict__ za_f8, const unsigned char* __restrict__ zt_perm,
    const int* __restrict__ pid,
    float* __restrict__ s_row, float* __restrict__ s_col,
    float* __restrict__ posv)
{
    __shared__ __align__(16) unsigned char Bs[2][8192];   // 2 x 8 KB
    __shared__ int   pidc[512];
    __shared__ float colsum[512];

    const int bid   = blockIdx.x;
    const int strip = bid & 15, band = bid >> 4;
    const int row0  = band * 128, scol0 = strip * 512;
    const int tid   = threadIdx.x, lane = tid & 63, wid = tid >> 6;
    const int q     = lane >> 4, lc = lane & 15;
    const int rbase = row0 + wid * 32;
    const int qs8   = (q ^ ((lc >> 2) & 3)) * 8;   // swizzled 8-B k-slot offset

    pidc[tid]         = pid[scol0 + tid];
    pidc[tid + 256]   = pid[scol0 + tid + 256];
    colsum[tid]       = 0.f;
    colsum[tid + 256] = 0.f;

    // A fragments resident: af[m][kc] = A[rbase+m*16+lc][kc*32 + q*8 ..+8] (fp8)
    fp8x8 af[2][8];
    #pragma unroll
    for (int m = 0; m < 2; m++) {
        const unsigned char* ga = za_f8 + (size_t)(rbase + m * 16 + lc) * DDIM + q * 8;
        #pragma unroll
        for (int kc = 0; kc < 8; kc++)
            af[m][kc] = *(const fp8x8*)(ga + kc * 32);
    }

    int prw[2][4];
    #pragma unroll
    for (int m = 0; m < 2; m++)
        #pragma unroll
        for (int r = 0; r < 4; r++)
            prw[m][r] = pid[rbase + m * 16 + q * 4 + r];

    // staging: 8KB chunk C (0..15) of this strip = zt_perm bytes
    // [(strip*32)*4096 + C*8192, +8192); 4 waves x 2 width-16 issues cover it.
    const unsigned char* zp = zt_perm + (size_t)(strip * 32) * 4096
                            + wid * 1024 + lane * 16;

#define STAGE(C, b)                                                              \
    do {                                                                         \
        const unsigned char* _s = zp + (size_t)(C) * 8192;                       \
        unsigned char* _d = &Bs[b][0] + wid * 1024;                              \
        __builtin_amdgcn_global_load_lds(                                        \
            (const __attribute__((address_space(1))) void*)_s,                   \
            (__attribute__((address_space(3))) void*)_d, 16, 0, 0);              \
        __builtin_amdgcn_global_load_lds(                                        \
            (const __attribute__((address_space(1))) void*)(_s + 4096),          \
            (__attribute__((address_space(3))) void*)(_d + 4096), 16, 0, 0);     \
    } while (0)

    STAGE(0, 0);   // prologue

    float rowp[8] = {0.f, 0.f, 0.f, 0.f, 0.f, 0.f, 0.f, 0.f};
    const int diag_t = (row0 - scol0) >> 7;   // tile holding the diagonal (if in [0,4))

    for (int t = 0; t < 4; t++) {
        floatx4 acc[2][8];
        #pragma unroll
        for (int m = 0; m < 2; m++)
            #pragma unroll
            for (int n = 0; n < 8; n++)
                acc[m][n] = (floatx4){0.f, 0.f, 0.f, 0.f};

        #pragma unroll
        for (int c2 = 0; c2 < 4; c2++) {
            __syncthreads();                 // chunk C landed (vmcnt drain at barrier)
            const int C = t * 4 + c2;
            if (C + 1 < 16) STAGE(C + 1, (C + 1) & 1);   // fire-and-forget prefetch

            const unsigned char* B = &Bs[C & 1][0];
            #pragma unroll
            for (int j = 0; j < 2; j++) {    // two 32-k sub-chunks of the 8KB
                const int kc = c2 * 2 + j;
                fp8x8 bfr[8];
                #pragma unroll
                for (int n = 0; n < 8; n++)
                    bfr[n] = *(const fp8x8*)(B + j * 4096 + (n * 16 + lc) * 32 + qs8);

                #pragma unroll
                for (int m = 0; m < 2; m++)
                    #pragma unroll
                    for (int n = 0; n < 8; n++)
                        acc[m][n] = __builtin_amdgcn_mfma_f32_16x16x32_fp8_fp8(
                            af[m][kc], bfr[n], acc[m][n], 0, 0, 0);
            }
        }

        // ---------- epilogue for tile t (next chunk's prefetch in flight)
        int pc[8];
        #pragma unroll
        for (int n = 0; n < 8; n++) pc[n] = pidc[t * 128 + n * 16 + lc];

        float colp[8] = {0.f, 0.f, 0.f, 0.f, 0.f, 0.f, 0.f, 0.f};
        #pragma unroll
        for (int m = 0; m < 2; m++) {
            #pragma unroll
            for (int r = 0; r < 4; r++) {
                const int pr = prw[m][r];
                float rsum = 0.f;
                #pragma unroll
                for (int n = 0; n < 8; n++) {
                    float e = __builtin_amdgcn_exp2f(fmaf(acc[m][n][r], SC_L2E, -C2));
                    e = (pr != pc[n]) ? e : 0.f;
                    rsum += e;
                    colp[n] += e;
                }
                rowp[m * 4 + r] += rsum;
            }
        }

        if (t == diag_t) {   // uniform branch: add back the (always same-pid) diagonal.
            // CONSTANT-INDEX select chains only — dynamic reg-array indexing
            // demotes acc[] to scratch (R5: 1.66 GB HBM writes, 3x regression).
            #pragma unroll
            for (int m = 0; m < 2; m++) {
                const int nstar = wid * 2 + m;          // runtime value, fine
                #pragma unroll
                for (int r = 0; r < 4; r++) {
                    float v = 0.f;
                    #pragma unroll
                    for (int n = 0; n < 8; n++)
                        v = (n == nstar) ? acc[m][n][r] : v;   // cndmask chain
                    float e = __builtin_amdgcn_exp2f(fmaf(v, SC_L2E, -C2));
                    const bool own = (lc == q * 4 + r);
                    e = own ? e : 0.f;
                    rowp[m * 4 + r] += e;
                    #pragma unroll
                    for (int n = 0; n < 8; n++)
                        colp[n] += (n == nstar) ? e : 0.f;     // cndmask chain
                    if (own) posv[rbase + m * 16 + q * 4 + r] = v * SCALE;
                }
            }
        }

        #pragma unroll
        for (int n = 0; n < 8; n++) {
            colp[n] += __shfl_xor(colp[n], 16, 64);
            colp[n] += __shfl_xor(colp[n], 32, 64);
        }
        if (q == 0) {
            #pragma unroll
            for (int n = 0; n < 8; n++)
                atomicAdd(&colsum[t * 128 + n * 16 + lc], colp[n]);
        }
    }

    // ---------- row sums: reduce over lc (cols), one atomic per row
    #pragma unroll
    for (int i = 0; i < 8; i++) {
        rowp[i] += __shfl_xor(rowp[i], 1, 64);
        rowp[i] += __shfl_xor(rowp[i], 2, 64);
        rowp[i] += __shfl_xor(rowp[i], 4, 64);
        rowp[i] += __shfl_xor(rowp[i], 8, 64);
    }
    float rw = rowp[0];
    #pragma unroll
    for (int idx = 1; idx < 8; idx++)
        rw = (lc == idx) ? rowp[idx] : rw;
    if (lc < 8)
        atomicAdd(&s_row[rbase + (lc >> 2) * 16 + q * 4 + (lc & 3)], rw);

    // ---------- col sums
    __syncthreads();
    atomicAdd(&s_col[scol0 + tid], colsum[tid]);
    atomicAdd(&s_col[scol0 + tid + 256], colsum[tid + 256]);
#undef STAGE
}

// ---------------------------------------------------------------- finalize (+ scalar write)
__global__ __launch_bounds__(256) void finalize_rows(
    const int* __restrict__ pid,
    const float* __restrict__ s_row, const float* __restrict__ s_col,
    const float* __restrict__ posv,
    float* __restrict__ total, int* __restrict__ flag, int* __restrict__ cnt,
    float* __restrict__ out)
{
    const int i = blockIdx.x * 256 + threadIdx.x;
    const float p = posv[i];
    const float c = (logf(s_row[i]) + C_OFF - p)
                  + (logf(s_col[i]) + C_OFF - p);

    float v = c;
    #pragma unroll
    for (int off = 32; off > 0; off >>= 1) v += __shfl_down(v, off, 64);
    if ((threadIdx.x & 63) == 0) atomicAdd(total, v);

    const unsigned long long m = __ballot(pid[i] != pid[0]);
    if (m != 0ull && (threadIdx.x & 63) == 0) atomicOr(flag, 1);

    __syncthreads();
    __threadfence();
    if (threadIdx.x == 0) {
        const int done = atomicAdd(cnt, 1);
        if (done == (int)gridDim.x - 1) {
            const float t = atomicAdd(total, 0.0f);
            const int   f = atomicOr(flag, 0);
            out[0] = f ? t / (2.0f * (float)BSZ) : 0.0f;
        }
    }
}

// ---------------------------------------------------------------- launcher
extern "C" void kernel_launch(void* const* d_in, const int* in_sizes, int n_in,
                              void* d_out, int out_size, void* d_ws, size_t ws_size,
                              hipStream_t stream)
{
    const float* za  = (const float*)d_in[0];
    const float* zt  = (const float*)d_in[1];
    const int*   pid = (const int*)d_in[2];
    float* out = (float*)d_out;

    // ws: za_f8 2MB | zt_perm 2MB | s_row[8192] s_col[8192] total flag cnt posv[8192]
    unsigned char* za_f8   = (unsigned char*)d_ws;
    unsigned char* zt_perm = za_f8 + (size_t)BSZ * DDIM;
    float*  s_row   = (float*)(zt_perm + (size_t)BSZ * DDIM);
    float*  s_col   = s_row + BSZ;
    float*  total   = s_col + BSZ;
    int*    flag    = (int*)(total + 1);
    int*    cnt     = flag + 1;
    float*  posv    = (float*)(cnt + 1);

    prep_kernel<<<dim3(2048), 256, 0, stream>>>(za, zt, za_f8, zt_perm, s_row);

    sim_fused<<<dim3(1024), 256, 0, stream>>>(za_f8, zt_perm, pid,
                                              s_row, s_col, posv);

    finalize_rows<<<dim3(BSZ / 256), 256, 0, stream>>>(
        pid, s_row, s_col, posv, total, flag, cnt, out);
}

// Round 16
// 119.140 us; speedup vs baseline: 1.0709x; 1.0092x over previous
//
#include <hip/hip_runtime.h>
#include <math.h>

#define BSZ    8192
#define DDIM   256
#define SCALE  33.33333333333333f   // 1/0.03
#define C_OFF  34.0f                // fixed LSE offset: |sim*SCALE| <= 33.34
#define SC_L2E 48.08983470f         // SCALE * log2(e)
#define C2     49.05163139f         // C_OFF * log2(e)

typedef float floatx4 __attribute__((ext_vector_type(4)));
typedef long long fp8x8;            // 8 x fp8 e4m3 = one MFMA operand (2 VGPRs)

// pack 8 fp32 -> 8 fp8 e4m3 (HW cvt; format matches the fp8 MFMA operand)
__device__ __forceinline__ fp8x8 cvt8_f8(const float* __restrict__ g)
{
    const float4 lo = *(const float4*)g;
    const float4 hi = *(const float4*)(g + 4);
    int a = __builtin_amdgcn_cvt_pk_fp8_f32(lo.x, lo.y, 0, false);
    a     = __builtin_amdgcn_cvt_pk_fp8_f32(lo.z, lo.w, a, true);
    int b = __builtin_amdgcn_cvt_pk_fp8_f32(hi.x, hi.y, 0, false);
    b     = __builtin_amdgcn_cvt_pk_fp8_f32(hi.z, hi.w, b, true);
    int2 r; r.x = a; r.y = b;
    return *(fp8x8*)&r;
}

// ---------------------------------------------------------------- prep (R13/R15-identical)
// blocks [0,1024): za -> za_f8 (row-major fp8) + zero reduction ws (first 17 blocks)
// blocks [1024,2048): zt -> zt_perm (fp8), chunk-ordered: 4KB unit = (cb, kc);
//   8-B slot P (0..511) holds col cb*128+(P>>2), k = kc*32 + ((P&3)^(((P>>2)>>2)&3))*8
//   (R13-verified conflict-free LDS image).
__global__ __launch_bounds__(256) void prep_kernel(
    const float* __restrict__ za, const float* __restrict__ zt,
    unsigned char* __restrict__ za_f8, unsigned char* __restrict__ zt_perm,
    float* __restrict__ zbase)
{
    const int bid = blockIdx.x, tid = threadIdx.x;
    if (bid < 1024) {
        const int i = (bid * 256 + tid) * 8;
        *(fp8x8*)(za_f8 + i) = cvt8_f8(za + i);
        if (bid < 16) {
            const int z = bid * 1024 + tid * 4;
            *(float4*)&zbase[z] = (float4){0.f, 0.f, 0.f, 0.f};
            if (bid == 0 && tid == 0) {
                zbase[16384] = 0.f;          // total
                ((int*)zbase)[16385] = 0;    // flag
                ((int*)zbase)[16386] = 0;    // cnt
            }
        }
    } else {
        const int S     = (bid - 1024) * 256 + tid;   // global 8-B slot id
        const int chunk = S >> 9, P = S & 511;
        const int col   = P >> 2, sp = P & 3;
        const int sl    = sp ^ ((col >> 2) & 3);
        const int cb    = chunk >> 3, kc = chunk & 7;
        const float* src = zt + (size_t)(cb * 128 + col) * DDIM + kc * 32 + sl * 8;
        *(fp8x8*)(zt_perm + (size_t)S * 8) = cvt8_f8(src);
    }
}

// ---------------------------------------------------------------- sim (R15 + ONE delta)
// SINGLE change vs R15 (best-known-good, sim 52.2us): 16KB staging chunks
// (4 global_load_lds issues/wave), 2x16KB buffers -> 8 K-loop barriers (was
// 16). Barrier-overhead rate measured at ~0.2us/barrier (R13->R15).
__global__ __launch_bounds__(256, 2) void sim_fused(
    const unsigned char* __restrict__ za_f8, const unsigned char* __restrict__ zt_perm,
    const int* __restrict__ pid,
    float* __restrict__ s_row, float* __restrict__ s_col,
    float* __restrict__ posv)
{
    __shared__ __align__(16) unsigned char Bs[2][16384];   // 2 x 16 KB
    __shared__ int   pidc[512];
    __shared__ float colsum[512];

    const int bid   = blockIdx.x;
    const int strip = bid & 15, band = bid >> 4;
    const int row0  = band * 128, scol0 = strip * 512;
    const int tid   = threadIdx.x, lane = tid & 63, wid = tid >> 6;
    const int q     = lane >> 4, lc = lane & 15;
    const int rbase = row0 + wid * 32;
    const int qs8   = (q ^ ((lc >> 2) & 3)) * 8;   // swizzled 8-B k-slot offset

    pidc[tid]         = pid[scol0 + tid];
    pidc[tid + 256]   = pid[scol0 + tid + 256];
    colsum[tid]       = 0.f;
    colsum[tid + 256] = 0.f;

    // A fragments resident: af[m][kc] = A[rbase+m*16+lc][kc*32 + q*8 ..+8] (fp8)
    fp8x8 af[2][8];
    #pragma unroll
    for (int m = 0; m < 2; m++) {
        const unsigned char* ga = za_f8 + (size_t)(rbase + m * 16 + lc) * DDIM + q * 8;
        #pragma unroll
        for (int kc = 0; kc < 8; kc++)
            af[m][kc] = *(const fp8x8*)(ga + kc * 32);
    }

    int prw[2][4];
    #pragma unroll
    for (int m = 0; m < 2; m++)
        #pragma unroll
        for (int r = 0; r < 4; r++)
            prw[m][r] = pid[rbase + m * 16 + q * 4 + r];

    // staging: 16KB chunk C (0..7) of this strip = zt_perm bytes
    // [(strip*32)*4096 + C*16384, +16384); 4 waves x 4 width-16 issues cover it.
    const unsigned char* zp = zt_perm + (size_t)(strip * 32) * 4096
                            + wid * 4096 + lane * 16;

#define STAGE(C, b)                                                              \
    do {                                                                         \
        const unsigned char* _s = zp + (size_t)(C) * 16384;                      \
        unsigned char* _d = &Bs[b][0] + wid * 4096;                              \
        _Pragma("unroll")                                                        \
        for (int _i = 0; _i < 4; _i++)                                           \
            __builtin_amdgcn_global_load_lds(                                    \
                (const __attribute__((address_space(1))) void*)(_s + _i * 1024), \
                (__attribute__((address_space(3))) void*)(_d + _i * 1024),       \
                16, 0, 0);                                                       \
    } while (0)

    STAGE(0, 0);   // prologue

    float rowp[8] = {0.f, 0.f, 0.f, 0.f, 0.f, 0.f, 0.f, 0.f};
    const int diag_t = (row0 - scol0) >> 7;   // tile holding the diagonal (if in [0,4))

    for (int t = 0; t < 4; t++) {
        floatx4 acc[2][8];
        #pragma unroll
        for (int m = 0; m < 2; m++)
            #pragma unroll
            for (int n = 0; n < 8; n++)
                acc[m][n] = (floatx4){0.f, 0.f, 0.f, 0.f};

        #pragma unroll
        for (int c2 = 0; c2 < 2; c2++) {     // two 16KB chunks per tile
            __syncthreads();                 // chunk C landed (vmcnt drain at barrier)
            const int C = t * 2 + c2;
            if (C + 1 < 8) STAGE(C + 1, (C + 1) & 1);   // fire-and-forget prefetch

            const unsigned char* B = &Bs[C & 1][0];
            #pragma unroll
            for (int j = 0; j < 4; j++) {    // four 32-k sub-chunks of the 16KB
                const int kc = c2 * 4 + j;
                fp8x8 bfr[8];
                #pragma unroll
                for (int n = 0; n < 8; n++)
                    bfr[n] = *(const fp8x8*)(B + j * 4096 + (n * 16 + lc) * 32 + qs8);

                #pragma unroll
                for (int m = 0; m < 2; m++)
                    #pragma unroll
                    for (int n = 0; n < 8; n++)
                        acc[m][n] = __builtin_amdgcn_mfma_f32_16x16x32_fp8_fp8(
                            af[m][kc], bfr[n], acc[m][n], 0, 0, 0);
            }
        }

        // ---------- epilogue for tile t (next chunk's prefetch in flight)
        int pc[8];
        #pragma unroll
        for (int n = 0; n < 8; n++) pc[n] = pidc[t * 128 + n * 16 + lc];

        float colp[8] = {0.f, 0.f, 0.f, 0.f, 0.f, 0.f, 0.f, 0.f};
        #pragma unroll
        for (int m = 0; m < 2; m++) {
            #pragma unroll
            for (int r = 0; r < 4; r++) {
                const int pr = prw[m][r];
                float rsum = 0.f;
                #pragma unroll
                for (int n = 0; n < 8; n++) {
                    float e = __builtin_amdgcn_exp2f(fmaf(acc[m][n][r], SC_L2E, -C2));
                    e = (pr != pc[n]) ? e : 0.f;
                    rsum += e;
                    colp[n] += e;
                }
                rowp[m * 4 + r] += rsum;
            }
        }

        if (t == diag_t) {   // uniform branch: add back the (always same-pid) diagonal.
            // CONSTANT-INDEX select chains only — dynamic reg-array indexing
            // demotes acc[] to scratch (R5: 1.66 GB HBM writes, 3x regression).
            #pragma unroll
            for (int m = 0; m < 2; m++) {
                const int nstar = wid * 2 + m;          // runtime value, fine
                #pragma unroll
                for (int r = 0; r < 4; r++) {
                    float v = 0.f;
                    #pragma unroll
                    for (int n = 0; n < 8; n++)
                        v = (n == nstar) ? acc[m][n][r] : v;   // cndmask chain
                    float e = __builtin_amdgcn_exp2f(fmaf(v, SC_L2E, -C2));
                    const bool own = (lc == q * 4 + r);
                    e = own ? e : 0.f;
                    rowp[m * 4 + r] += e;
                    #pragma unroll
                    for (int n = 0; n < 8; n++)
                        colp[n] += (n == nstar) ? e : 0.f;     // cndmask chain
                    if (own) posv[rbase + m * 16 + q * 4 + r] = v * SCALE;
                }
            }
        }

        #pragma unroll
        for (int n = 0; n < 8; n++) {
            colp[n] += __shfl_xor(colp[n], 16, 64);
            colp[n] += __shfl_xor(colp[n], 32, 64);
        }
        if (q == 0) {
            #pragma unroll
            for (int n = 0; n < 8; n++)
                atomicAdd(&colsum[t * 128 + n * 16 + lc], colp[n]);
        }
    }

    // ---------- row sums: reduce over lc (cols), one atomic per row
    #pragma unroll
    for (int i = 0; i < 8; i++) {
        rowp[i] += __shfl_xor(rowp[i], 1, 64);
        rowp[i] += __shfl_xor(rowp[i], 2, 64);
        rowp[i] += __shfl_xor(rowp[i], 4, 64);
        rowp[i] += __shfl_xor(rowp[i], 8, 64);
    }
    float rw = rowp[0];
    #pragma unroll
    for (int idx = 1; idx < 8; idx++)
        rw = (lc == idx) ? rowp[idx] : rw;
    if (lc < 8)
        atomicAdd(&s_row[rbase + (lc >> 2) * 16 + q * 4 + (lc & 3)], rw);

    // ---------- col sums
    __syncthreads();
    atomicAdd(&s_col[scol0 + tid], colsum[tid]);
    atomicAdd(&s_col[scol0 + tid + 256], colsum[tid + 256]);
#undef STAGE
}

// ---------------------------------------------------------------- finalize (+ scalar write)
__global__ __launch_bounds__(256) void finalize_rows(
    const int* __restrict__ pid,
    const float* __restrict__ s_row, const float* __restrict__ s_col,
    const float* __restrict__ posv,
    float* __restrict__ total, int* __restrict__ flag, int* __restrict__ cnt,
    float* __restrict__ out)
{
    const int i = blockIdx.x * 256 + threadIdx.x;
    const float p = posv[i];
    const float c = (logf(s_row[i]) + C_OFF - p)
                  + (logf(s_col[i]) + C_OFF - p);

    float v = c;
    #pragma unroll
    for (int off = 32; off > 0; off >>= 1) v += __shfl_down(v, off, 64);
    if ((threadIdx.x & 63) == 0) atomicAdd(total, v);

    const unsigned long long m = __ballot(pid[i] != pid[0]);
    if (m != 0ull && (threadIdx.x & 63) == 0) atomicOr(flag, 1);

    __syncthreads();
    __threadfence();
    if (threadIdx.x == 0) {
        const int done = atomicAdd(cnt, 1);
        if (done == (int)gridDim.x - 1) {
            const float t = atomicAdd(total, 0.0f);
            const int   f = atomicOr(flag, 0);
            out[0] = f ? t / (2.0f * (float)BSZ) : 0.0f;
        }
    }
}

// ---------------------------------------------------------------- launcher
extern "C" void kernel_launch(void* const* d_in, const int* in_sizes, int n_in,
                              void* d_out, int out_size, void* d_ws, size_t ws_size,
                              hipStream_t stream)
{
    const float* za  = (const float*)d_in[0];
    const float* zt  = (const float*)d_in[1];
    const int*   pid = (const int*)d_in[2];
    float* out = (float*)d_out;

    // ws: za_f8 2MB | zt_perm 2MB | s_row[8192] s_col[8192] total flag cnt posv[8192]
    unsigned char* za_f8   = (unsigned char*)d_ws;
    unsigned char* zt_perm = za_f8 + (size_t)BSZ * DDIM;
    float*  s_row   = (float*)(zt_perm + (size_t)BSZ * DDIM);
    float*  s_col   = s_row + BSZ;
    float*  total   = s_col + BSZ;
    int*    flag    = (int*)(total + 1);
    int*    cnt     = flag + 1;
    float*  posv    = (float*)(cnt + 1);

    prep_kernel<<<dim3(2048), 256, 0, stream>>>(za, zt, za_f8, zt_perm, s_row);

    sim_fused<<<dim3(1024), 256, 0, stream>>>(za_f8, zt_perm, pid,
                                              s_row, s_col, posv);

    finalize_rows<<<dim3(BSZ / 256), 256, 0, stream>>>(
        pid, s_row, s_col, posv, total, flag, cnt, out);
}

// Round 17
// 118.380 us; speedup vs baseline: 1.0778x; 1.0064x over previous
//
#include <hip/hip_runtime.h>
#include <math.h>

#define BSZ    8192
#define DDIM   256
#define SCALE  33.33333333333333f   // 1/0.03
#define C_OFF  34.0f                // fixed LSE offset: |sim*SCALE| <= 33.34
#define SC_L2E 48.08983470f         // SCALE * log2(e)
#define C2     49.05163139f         // C_OFF * log2(e)

typedef float floatx4 __attribute__((ext_vector_type(4)));
typedef long long fp8x8;            // 8 x fp8 e4m3 = one MFMA operand (2 VGPRs)

// pack 8 fp32 -> 8 fp8 e4m3 (HW cvt; format matches the fp8 MFMA operand)
__device__ __forceinline__ fp8x8 cvt8_f8(const float* __restrict__ g)
{
    const float4 lo = *(const float4*)g;
    const float4 hi = *(const float4*)(g + 4);
    int a = __builtin_amdgcn_cvt_pk_fp8_f32(lo.x, lo.y, 0, false);
    a     = __builtin_amdgcn_cvt_pk_fp8_f32(lo.z, lo.w, a, true);
    int b = __builtin_amdgcn_cvt_pk_fp8_f32(hi.x, hi.y, 0, false);
    b     = __builtin_amdgcn_cvt_pk_fp8_f32(hi.z, hi.w, b, true);
    int2 r; r.x = a; r.y = b;
    return *(fp8x8*)&r;
}

// ---------------------------------------------------------------- prep (R13/R15/R16-identical)
__global__ __launch_bounds__(256) void prep_kernel(
    const float* __restrict__ za, const float* __restrict__ zt,
    unsigned char* __restrict__ za_f8, unsigned char* __restrict__ zt_perm,
    float* __restrict__ zbase)
{
    const int bid = blockIdx.x, tid = threadIdx.x;
    if (bid < 1024) {
        const int i = (bid * 256 + tid) * 8;
        *(fp8x8*)(za_f8 + i) = cvt8_f8(za + i);
        if (bid < 16) {
            const int z = bid * 1024 + tid * 4;
            *(float4*)&zbase[z] = (float4){0.f, 0.f, 0.f, 0.f};
            if (bid == 0 && tid == 0) {
                zbase[16384] = 0.f;          // total
                ((int*)zbase)[16385] = 0;    // flag
                ((int*)zbase)[16386] = 0;    // cnt
            }
        }
    } else {
        const int S     = (bid - 1024) * 256 + tid;   // global 8-B slot id
        const int chunk = S >> 9, P = S & 511;
        const int col   = P >> 2, sp = P & 3;
        const int sl    = sp ^ ((col >> 2) & 3);
        const int cb    = chunk >> 3, kc = chunk & 7;
        const float* src = zt + (size_t)(cb * 128 + col) * DDIM + kc * 32 + sl * 8;
        *(fp8x8*)(zt_perm + (size_t)S * 8) = cvt8_f8(src);
    }
}

// ---------------------------------------------------------------- sim (R16 + ONE delta)
// SINGLE change vs R16 (best-known-good, sim ~53us): K-loop barriers are raw
// `s_barrier` + per-wave `s_waitcnt vmcnt(4)` instead of __syncthreads, with
// 3 rotating 16KB buffers (WAR-safe). The just-issued prefetch stays in
// flight across the barrier — the compiler's vmcnt(0) drain is gone.
// Correctness: each wave stages its own quarter and drains its OWN loads
// (vmcnt(4)) before s_barrier -> all chunk-C data visible after barrier.
// One __syncthreads before the loop drains prologue (chunk0/af/pidc).
__global__ __launch_bounds__(256, 2) void sim_fused(
    const unsigned char* __restrict__ za_f8, const unsigned char* __restrict__ zt_perm,
    const int* __restrict__ pid,
    float* __restrict__ s_row, float* __restrict__ s_col,
    float* __restrict__ posv)
{
    __shared__ __align__(16) unsigned char Bs[3][16384];   // 3 x 16 KB rotating
    __shared__ int   pidc[512];
    __shared__ float colsum[512];

    const int bid   = blockIdx.x;
    const int strip = bid & 15, band = bid >> 4;
    const int row0  = band * 128, scol0 = strip * 512;
    const int tid   = threadIdx.x, lane = tid & 63, wid = tid >> 6;
    const int q     = lane >> 4, lc = lane & 15;
    const int rbase = row0 + wid * 32;
    const int qs8   = (q ^ ((lc >> 2) & 3)) * 8;   // swizzled 8-B k-slot offset

    pidc[tid]         = pid[scol0 + tid];
    pidc[tid + 256]   = pid[scol0 + tid + 256];
    colsum[tid]       = 0.f;
    colsum[tid + 256] = 0.f;

    // A fragments resident: af[m][kc] = A[rbase+m*16+lc][kc*32 + q*8 ..+8] (fp8)
    fp8x8 af[2][8];
    #pragma unroll
    for (int m = 0; m < 2; m++) {
        const unsigned char* ga = za_f8 + (size_t)(rbase + m * 16 + lc) * DDIM + q * 8;
        #pragma unroll
        for (int kc = 0; kc < 8; kc++)
            af[m][kc] = *(const fp8x8*)(ga + kc * 32);
    }

    int prw[2][4];
    #pragma unroll
    for (int m = 0; m < 2; m++)
        #pragma unroll
        for (int r = 0; r < 4; r++)
            prw[m][r] = pid[rbase + m * 16 + q * 4 + r];

    // staging: 16KB chunk C (0..7) of this strip; 4 waves x 4 width-16 issues.
    const unsigned char* zp = zt_perm + (size_t)(strip * 32) * 4096
                            + wid * 4096 + lane * 16;

#define STAGE(C, bufi)                                                           \
    do {                                                                         \
        const unsigned char* _s = zp + (size_t)(C) * 16384;                      \
        unsigned char* _d = &Bs[0][0] + (bufi) * 16384 + wid * 4096;             \
        _Pragma("unroll")                                                        \
        for (int _i = 0; _i < 4; _i++)                                           \
            __builtin_amdgcn_global_load_lds(                                    \
                (const __attribute__((address_space(1))) void*)(_s + _i * 1024), \
                (__attribute__((address_space(3))) void*)(_d + _i * 1024),       \
                16, 0, 0);                                                       \
    } while (0)

    STAGE(0, 0);       // prologue: chunk 0 -> buf 0
    __syncthreads();   // one-time full drain: chunk0 + af + pidc all visible

    float rowp[8] = {0.f, 0.f, 0.f, 0.f, 0.f, 0.f, 0.f, 0.f};
    const int diag_t = (row0 - scol0) >> 7;   // tile holding the diagonal (if in [0,4))
    int bcur = 0;                              // chunk C lives in buf C%3

    for (int t = 0; t < 4; t++) {
        floatx4 acc[2][8];
        #pragma unroll
        for (int m = 0; m < 2; m++)
            #pragma unroll
            for (int n = 0; n < 8; n++)
                acc[m][n] = (floatx4){0.f, 0.f, 0.f, 0.f};

        #pragma unroll
        for (int c2 = 0; c2 < 2; c2++) {     // two 16KB chunks per tile
            const int C    = t * 2 + c2;
            const int bnxt = (bcur == 2) ? 0 : bcur + 1;
            if (C < 7) {
                STAGE(C + 1, bnxt);          // fire-and-forget prefetch (4 loads)
                // drain ONLY chunk C's 4 loads; C+1's 4 stay in flight
                __asm__ volatile("s_waitcnt vmcnt(4)" ::: "memory");
            } else {
                __asm__ volatile("s_waitcnt vmcnt(0)" ::: "memory");
            }
            // raw barrier: no compiler vmcnt(0) drain (the R16 stall)
            __asm__ volatile("s_barrier" ::: "memory");

            const unsigned char* B = &Bs[0][0] + bcur * 16384;
            #pragma unroll
            for (int j = 0; j < 4; j++) {    // four 32-k sub-chunks of the 16KB
                const int kc = c2 * 4 + j;
                fp8x8 bfr[8];
                #pragma unroll
                for (int n = 0; n < 8; n++)
                    bfr[n] = *(const fp8x8*)(B + j * 4096 + (n * 16 + lc) * 32 + qs8);

                #pragma unroll
                for (int m = 0; m < 2; m++)
                    #pragma unroll
                    for (int n = 0; n < 8; n++)
                        acc[m][n] = __builtin_amdgcn_mfma_f32_16x16x32_fp8_fp8(
                            af[m][kc], bfr[n], acc[m][n], 0, 0, 0);
            }
            bcur = bnxt;
        }

        // ---------- epilogue for tile t (next chunk's prefetch in flight)
        int pc[8];
        #pragma unroll
        for (int n = 0; n < 8; n++) pc[n] = pidc[t * 128 + n * 16 + lc];

        float colp[8] = {0.f, 0.f, 0.f, 0.f, 0.f, 0.f, 0.f, 0.f};
        #pragma unroll
        for (int m = 0; m < 2; m++) {
            #pragma unroll
            for (int r = 0; r < 4; r++) {
                const int pr = prw[m][r];
                float rsum = 0.f;
                #pragma unroll
                for (int n = 0; n < 8; n++) {
                    float e = __builtin_amdgcn_exp2f(fmaf(acc[m][n][r], SC_L2E, -C2));
                    e = (pr != pc[n]) ? e : 0.f;
                    rsum += e;
                    colp[n] += e;
                }
                rowp[m * 4 + r] += rsum;
            }
        }

        if (t == diag_t) {   // diagonal fixup — constant-index select chains only
            #pragma unroll      // (R5 lesson: dynamic reg-array indexing = scratch)
            for (int m = 0; m < 2; m++) {
                const int nstar = wid * 2 + m;
                #pragma unroll
                for (int r = 0; r < 4; r++) {
                    float v = 0.f;
                    #pragma unroll
                    for (int n = 0; n < 8; n++)
                        v = (n == nstar) ? acc[m][n][r] : v;   // cndmask chain
                    float e = __builtin_amdgcn_exp2f(fmaf(v, SC_L2E, -C2));
                    const bool own = (lc == q * 4 + r);
                    e = own ? e : 0.f;
                    rowp[m * 4 + r] += e;
                    #pragma unroll
                    for (int n = 0; n < 8; n++)
                        colp[n] += (n == nstar) ? e : 0.f;     // cndmask chain
                    if (own) posv[rbase + m * 16 + q * 4 + r] = v * SCALE;
                }
            }
        }

        #pragma unroll
        for (int n = 0; n < 8; n++) {
            colp[n] += __shfl_xor(colp[n], 16, 64);
            colp[n] += __shfl_xor(colp[n], 32, 64);
        }
        if (q == 0) {
            #pragma unroll
            for (int n = 0; n < 8; n++)
                atomicAdd(&colsum[t * 128 + n * 16 + lc], colp[n]);
        }
    }

    // ---------- row sums: reduce over lc (cols), one atomic per row
    #pragma unroll
    for (int i = 0; i < 8; i++) {
        rowp[i] += __shfl_xor(rowp[i], 1, 64);
        rowp[i] += __shfl_xor(rowp[i], 2, 64);
        rowp[i] += __shfl_xor(rowp[i], 4, 64);
        rowp[i] += __shfl_xor(rowp[i], 8, 64);
    }
    float rw = rowp[0];
    #pragma unroll
    for (int idx = 1; idx < 8; idx++)
        rw = (lc == idx) ? rowp[idx] : rw;
    if (lc < 8)
        atomicAdd(&s_row[rbase + (lc >> 2) * 16 + q * 4 + (lc & 3)], rw);

    // ---------- col sums
    __syncthreads();
    atomicAdd(&s_col[scol0 + tid], colsum[tid]);
    atomicAdd(&s_col[scol0 + tid + 256], colsum[tid + 256]);
#undef STAGE
}

// ---------------------------------------------------------------- finalize (+ scalar write)
__global__ __launch_bounds__(256) void finalize_rows(
    const int* __restrict__ pid,
    const float* __restrict__ s_row, const float* __restrict__ s_col,
    const float* __restrict__ posv,
    float* __restrict__ total, int* __restrict__ flag, int* __restrict__ cnt,
    float* __restrict__ out)
{
    const int i = blockIdx.x * 256 + threadIdx.x;
    const float p = posv[i];
    const float c = (logf(s_row[i]) + C_OFF - p)
                  + (logf(s_col[i]) + C_OFF - p);

    float v = c;
    #pragma unroll
    for (int off = 32; off > 0; off >>= 1) v += __shfl_down(v, off, 64);
    if ((threadIdx.x & 63) == 0) atomicAdd(total, v);

    const unsigned long long m = __ballot(pid[i] != pid[0]);
    if (m != 0ull && (threadIdx.x & 63) == 0) atomicOr(flag, 1);

    __syncthreads();
    __threadfence();
    if (threadIdx.x == 0) {
        const int done = atomicAdd(cnt, 1);
        if (done == (int)gridDim.x - 1) {
            const float t = atomicAdd(total, 0.0f);
            const int   f = atomicOr(flag, 0);
            out[0] = f ? t / (2.0f * (float)BSZ) : 0.0f;
        }
    }
}

// ---------------------------------------------------------------- launcher
extern "C" void kernel_launch(void* const* d_in, const int* in_sizes, int n_in,
                              void* d_out, int out_size, void* d_ws, size_t ws_size,
                              hipStream_t stream)
{
    const float* za  = (const float*)d_in[0];
    const float* zt  = (const float*)d_in[1];
    const int*   pid = (const int*)d_in[2];
    float* out = (float*)d_out;

    // ws: za_f8 2MB | zt_perm 2MB | s_row[8192] s_col[8192] total flag cnt posv[8192]
    unsigned char* za_f8   = (unsigned char*)d_ws;
    unsigned char* zt_perm = za_f8 + (size_t)BSZ * DDIM;
    float*  s_row   = (float*)(zt_perm + (size_t)BSZ * DDIM);
    float*  s_col   = s_row + BSZ;
    float*  total   = s_col + BSZ;
    int*    flag    = (int*)(total + 1);
    int*    cnt     = flag + 1;
    float*  posv    = (float*)(cnt + 1);

    prep_kernel<<<dim3(2048), 256, 0, stream>>>(za, zt, za_f8, zt_perm, s_row);

    sim_fused<<<dim3(1024), 256, 0, stream>>>(za_f8, zt_perm, pid,
                                              s_row, s_col, posv);

    finalize_rows<<<dim3(BSZ / 256), 256, 0, stream>>>(
        pid, s_row, s_col, posv, total, flag, cnt, out);
}